// Round 15
// baseline (86.723 us; speedup 1.0000x reference)
//
#include <hip/hip_runtime.h>
#include <math.h>

#define D_   363
#define A_   180
#define B_   4
#define IMG_ 256
#define W_   36   // window width: span<=30.12, base=floor(4corner min)-1 -> idx<=32, idx+1<=33

// ---------------------------------------------------------------------------
// Kernel 1: ramp filter as circular convolution, h in closed form.
//   filtered[n] = sum_m s[m] * h[(n-m) mod D]
//   h[n] = (4/D^2) * [182 cos(181*th) - 181 cos(182*th) - 1] / (4 sin^2(th/2)),
//     th = 2*pi*n/D;  h[0] = 2*181*182/D^2.  (verified vs FFT definition)
// One block per (batch,angle) row, 384 threads (363 compute lanes).
// s-taps are wave-uniform (blockIdx row + loop counter) -> uniform global
// loads on the scalar pipe; h-taps via per-lane ds_read_b128 of the
// pre-shifted float4 table. 90 quad iterations + 3-tap tail (no OOB).
// Index algebra: hext4[j][c] = h[(j-c) mod D]; quad q needs j = tid + D - 4q.
// ---------------------------------------------------------------------------
__global__ __launch_bounds__(384)
void fbp_filter(const float* __restrict__ sino,
                float* __restrict__ filtered) {
    __shared__ float                hval[D_];
    __shared__ __align__(16) float4 hext4[2 * D_];
    const int r   = blockIdx.x;      // 0 .. B_*A_-1
    const int tid = threadIdx.x;

    if (tid < D_) {
        float hn;
        if (tid == 0) {
            hn = 65884.0f / 131769.0f;          // 2*181*182 / 363^2
        } else {
            int p1 = (181 * tid) % D_;
            int p2 = (182 * tid) % D_;
            float c1 = cosf(6.28318530717958647692f * ((float)p1 * (1.0f / 363.0f)));
            float c2 = cosf(6.28318530717958647692f * ((float)p2 * (1.0f / 363.0f)));
            float sh = sinf(3.14159265358979323846f * ((float)tid * (1.0f / 363.0f)));
            float S  = (182.0f * c1 - 181.0f * c2 - 1.0f) / (4.0f * sh * sh);
            hn = S * (4.0f / 131769.0f);
        }
        hval[tid] = hn;
    }
    __syncthreads();

    for (int j = tid; j < 2 * D_; j += 384) {
        float a = hval[ j            % D_];
        float b = hval[(j + D_ - 1)  % D_];
        float c = hval[(j + D_ - 2)  % D_];
        float d = hval[(j + D_ - 3)  % D_];
        hext4[j] = make_float4(a, b, c, d);
    }
    __syncthreads();

    if (tid < D_) {
        const float* __restrict__ sg = sino + r * D_;   // uniform-index reads
        float acc = 0.0f;
        #pragma unroll 6
        for (int q = 0; q < 90; ++q) {
            float s0 = sg[4 * q];
            float s1 = sg[4 * q + 1];
            float s2 = sg[4 * q + 2];
            float s3 = sg[4 * q + 3];
            float4 hv = hext4[tid + D_ - 4 * q];        // per-lane b128
            acc = fmaf(s0, hv.x, acc);
            acc = fmaf(s1, hv.y, acc);
            acc = fmaf(s2, hv.z, acc);
            acc = fmaf(s3, hv.w, acc);
        }
        {   // tail m = 360,361,362:  j = tid + D - 360 = tid + 3
            float4 hv = hext4[tid + 3];
            acc = fmaf(sg[360], hv.x, acc);
            acc = fmaf(sg[361], hv.y, acc);
            acc = fmaf(sg[362], hv.z, acc);
        }
        filtered[r * D_ + tid] = acc;
    }
}

// ---------------------------------------------------------------------------
// Kernel 2: backprojection, 16x16 tiles, zero-padded LDS windows.
// Staging writes 0 where detector index is outside [0,362]; the hot loop is
// then mask-free and clamp-free:
//   pr  = x*C + y*S + off,  off = 181 - base  (window-relative px, >=0)
//   acc += win[idx]*(1-fr) + win[idx+1]*fr
// Out-of-range contributions become tap=0 instead of weight=0 -> identical
// values (fmaf(0,w,acc)=acc). base = floor(4-corner-min px) - 1 (fma monotone
// => bounds every lane; -1 absorbs the off-folding rounding delta).
// ---------------------------------------------------------------------------
__global__ __launch_bounds__(256)
void fbp_backproj(const float* __restrict__ filtered,
                  float* __restrict__ out) {
    __shared__ float4 csb[A_];          // {181*cos, 181*sin, 181-base, 0}
    __shared__ float  win[A_ * W_];     // zero-padded windows
    __shared__ int    baseA[A_];
    const int tid  = threadIdx.x;
    const int tile = blockIdx.x & 255;
    const int b    = blockIdx.x >> 8;
    const int ty   = tid >> 4, tx = tid & 15;
    const int r0   = ((tile >> 4) << 4);
    const int c0   = ((tile & 15) << 4);
    const int i = r0 + ty;
    const int j = c0 + tx;

    if (tid < A_) {
        float a = (float)((double)tid * (3.14159265358979323846 / 179.0));
        float sn, cn;
        sincosf(a, &sn, &cn);
        float C = 181.0f * cn, S = 181.0f * sn;
        float xa = -1.0f + 2.0f * (float)c0        / 255.0f;
        float xb = -1.0f + 2.0f * (float)(c0 + 15) / 255.0f;
        float ya = -1.0f + 2.0f * (float)r0        / 255.0f;
        float yb = -1.0f + 2.0f * (float)(r0 + 15) / 255.0f;
        float p00 = fmaf(xa, C, fmaf(ya, S, 181.0f));
        float p01 = fmaf(xb, C, fmaf(ya, S, 181.0f));
        float p10 = fmaf(xa, C, fmaf(yb, S, 181.0f));
        float p11 = fmaf(xb, C, fmaf(yb, S, 181.0f));
        float pmin = fminf(fminf(p00, p01), fminf(p10, p11));
        float base = floorf(pmin) - 1.0f;          // integer-valued, safety -1
        csb[tid]   = make_float4(C, S, 181.0f - base, 0.0f);
        baseA[tid] = (int)base;
    }
    __syncthreads();

    const float* __restrict__ fb = filtered + b * (A_ * D_);
    for (int u = tid; u < A_ * W_; u += 256) {
        int a = u / W_;                     // magic-mul
        int w = u - a * W_;
        int p = baseA[a] + w;
        win[u] = ((unsigned)p <= (unsigned)(D_ - 1)) ? fb[a * D_ + p] : 0.0f;
    }
    __syncthreads();

    const float y = -1.0f + 2.0f * (float)i / 255.0f;
    const float x = -1.0f + 2.0f * (float)j / 255.0f;
    float acc = 0.0f;

    #pragma unroll 4
    for (int a = 0; a < A_; ++a) {
        float4 cb = csb[a];                              // broadcast b128
        float pr = fmaf(x, cb.x, fmaf(y, cb.y, cb.z));   // window-relative px
        float fi = floorf(pr);
        float fr = pr - fi;
        int idx  = (int)fi;                              // in [0, 33]
        const float* wrow = &win[a * W_];
        acc = fmaf(wrow[idx],     1.0f - fr, acc);
        acc = fmaf(wrow[idx + 1], fr,        acc);
    }
    out[(b << 16) + i * IMG_ + j] = acc * (float)(M_PI / 180.0);
}

// ---------------------------------------------------------------------------
extern "C" void kernel_launch(void* const* d_in, const int* in_sizes, int n_in,
                              void* d_out, int out_size, void* d_ws, size_t ws_size,
                              hipStream_t stream) {
    const float* sino = (const float*)d_in[0];
    float* out = (float*)d_out;
    float* filtered = (float*)d_ws;   // B*A*D = 261360 floats (~1.05 MB)

    fbp_filter  <<<B_ * A_,   384, 0, stream>>>(sino, filtered);
    fbp_backproj<<<B_ * IMG_, 256, 0, stream>>>(filtered, out);
}

// Round 18
// 80.699 us; speedup vs baseline: 1.0746x; 1.0746x over previous
//
#include <hip/hip_runtime.h>
#include <math.h>

#define D_   363
#define A_   180
#define B_   4
#define IMG_ 256
#define W_   36   // window width: span<=30.12, base=floor(4corner min)-1 -> idx<=32, idx+1<=33

// ---------------------------------------------------------------------------
// Kernel 1: ramp filter as circular convolution, h in closed form.
//   filtered[n] = sum_m s[m] * h[(n-m) mod D]
//   h[n] = (4/D^2) * [182 cos(181*th) - 181 cos(182*th) - 1] / (4 sin^2(th/2)),
//     th = 2*pi*n/D;  h[0] = 2*181*182/D^2.  (verified vs FFT definition)
// One block per (batch,angle) row, 384 threads (363 compute lanes).
// s-taps wave-uniform -> scalar-pipe global loads; h-taps per-lane b128.
// Side job: blocks r<180 also write the angle table {181cos, 181sin} used by
// backproj's scalar-pipe loads (lane 368, idle in compute).
// ---------------------------------------------------------------------------
__global__ __launch_bounds__(384)
void fbp_filter(const float* __restrict__ sino,
                float* __restrict__ filtered,
                float2* __restrict__ cs_tab) {
    __shared__ float                hval[D_];
    __shared__ __align__(16) float4 hext4[2 * D_];
    const int r   = blockIdx.x;      // 0 .. B_*A_-1
    const int tid = threadIdx.x;

    if (tid < D_) {
        float hn;
        if (tid == 0) {
            hn = 65884.0f / 131769.0f;          // 2*181*182 / 363^2
        } else {
            int p1 = (181 * tid) % D_;
            int p2 = (182 * tid) % D_;
            float c1 = cosf(6.28318530717958647692f * ((float)p1 * (1.0f / 363.0f)));
            float c2 = cosf(6.28318530717958647692f * ((float)p2 * (1.0f / 363.0f)));
            float sh = sinf(3.14159265358979323846f * ((float)tid * (1.0f / 363.0f)));
            float S  = (182.0f * c1 - 181.0f * c2 - 1.0f) / (4.0f * sh * sh);
            hn = S * (4.0f / 131769.0f);
        }
        hval[tid] = hn;
    }
    if (r < A_ && tid == 368) {      // angles = linspace(0, pi, 180)
        float a = (float)((double)r * (3.14159265358979323846 / 179.0));
        float sn, cn;
        sincosf(a, &sn, &cn);
        cs_tab[r] = make_float2(181.0f * cn, 181.0f * sn);
    }
    __syncthreads();

    for (int j = tid; j < 2 * D_; j += 384) {
        float a = hval[ j            % D_];
        float b = hval[(j + D_ - 1)  % D_];
        float c = hval[(j + D_ - 2)  % D_];
        float d = hval[(j + D_ - 3)  % D_];
        hext4[j] = make_float4(a, b, c, d);
    }
    __syncthreads();

    if (tid < D_) {
        const float* __restrict__ sg = sino + r * D_;   // uniform-index reads
        float acc = 0.0f;
        #pragma unroll 6
        for (int q = 0; q < 90; ++q) {
            float s0 = sg[4 * q];
            float s1 = sg[4 * q + 1];
            float s2 = sg[4 * q + 2];
            float s3 = sg[4 * q + 3];
            float4 hv = hext4[tid + D_ - 4 * q];        // per-lane b128
            acc = fmaf(s0, hv.x, acc);
            acc = fmaf(s1, hv.y, acc);
            acc = fmaf(s2, hv.z, acc);
            acc = fmaf(s3, hv.w, acc);
        }
        {   // tail m = 360,361,362:  j = tid + D - 360 = tid + 3
            float4 hv = hext4[tid + 3];
            acc = fmaf(sg[360], hv.x, acc);
            acc = fmaf(sg[361], hv.y, acc);
            acc = fmaf(sg[362], hv.z, acc);
        }
        filtered[r * D_ + tid] = acc;
    }
}

// ---------------------------------------------------------------------------
// Kernel 2: backprojection, 16x16 tiles, zero-padded LDS windows.
// Hot-loop pipe budget per angle per wave (the R15 null showed LDS binds):
//   {C,S}: global, wave-uniform address -> s_load (scalar pipe, 0 LDS)
//   off:   LDS b32 broadcast (5.8 cyc)      [was: float4 b128, 12 cyc]
//   taps:  2x LDS b32 (11.6 cyc)
//   VALU:  2 fma (pr) + fract + cvt + addr + sub + 2 fma = 8 inst (16 cyc)
// pr = px - base >= 0.999 by construction (base = floor(4corner min)-1, fma
// monotone), so trunc == floor and fract is exact; lerp is continuous in pr
// so the +-1ulp off-folding perturbation is harmless (same as R14/R15).
// Out-of-range taps are 0 by staging -> mask-free, clamp-free loop.
// ---------------------------------------------------------------------------
__global__ __launch_bounds__(256)
void fbp_backproj(const float* __restrict__ filtered,
                  const float2* __restrict__ cst,
                  float* __restrict__ out) {
    __shared__ float win[A_ * W_];      // zero-padded windows
    __shared__ float offA[A_];          // 181 - base  (integer-valued float)
    __shared__ int   baseA[A_];
    const int tid  = threadIdx.x;
    const int tile = blockIdx.x & 255;
    const int b    = blockIdx.x >> 8;
    const int ty   = tid >> 4, tx = tid & 15;
    const int r0   = ((tile >> 4) << 4);
    const int c0   = ((tile & 15) << 4);
    const int i = r0 + ty;
    const int j = c0 + tx;

    if (tid < A_) {
        float2 cs = cst[tid];                    // coalesced float2
        float C = cs.x, S = cs.y;
        float xa = -1.0f + 2.0f * (float)c0        / 255.0f;
        float xb = -1.0f + 2.0f * (float)(c0 + 15) / 255.0f;
        float ya = -1.0f + 2.0f * (float)r0        / 255.0f;
        float yb = -1.0f + 2.0f * (float)(r0 + 15) / 255.0f;
        float p00 = fmaf(xa, C, fmaf(ya, S, 181.0f));
        float p01 = fmaf(xb, C, fmaf(ya, S, 181.0f));
        float p10 = fmaf(xa, C, fmaf(yb, S, 181.0f));
        float p11 = fmaf(xb, C, fmaf(yb, S, 181.0f));
        float pmin = fminf(fminf(p00, p01), fminf(p10, p11));
        float base = floorf(pmin) - 1.0f;        // integer-valued, safety -1
        offA[tid]  = 181.0f - base;
        baseA[tid] = (int)base;
    }
    __syncthreads();

    const float* __restrict__ fb = filtered + b * (A_ * D_);
    for (int u = tid; u < A_ * W_; u += 256) {
        int a = u / W_;                     // magic-mul
        int w = u - a * W_;
        int p = baseA[a] + w;
        win[u] = ((unsigned)p <= (unsigned)(D_ - 1)) ? fb[a * D_ + p] : 0.0f;
    }
    __syncthreads();

    const float y = -1.0f + 2.0f * (float)i / 255.0f;
    const float x = -1.0f + 2.0f * (float)j / 255.0f;
    float acc = 0.0f;

    #pragma unroll 4
    for (int a = 0; a < A_; ++a) {
        float2 cs = cst[a];                              // uniform -> s_load
        float pr = fmaf(x, cs.x, fmaf(y, cs.y, offA[a])); // window-relative px
        float fr = __builtin_amdgcn_fractf(pr);          // pr - floor(pr), exact
        int idx  = (int)pr;                              // trunc == floor (pr>=0.999)
        const float* wrow = &win[a * W_];
        acc = fmaf(wrow[idx],     1.0f - fr, acc);
        acc = fmaf(wrow[idx + 1], fr,        acc);
    }
    out[(b << 16) + i * IMG_ + j] = acc * (float)(M_PI / 180.0);
}

// ---------------------------------------------------------------------------
extern "C" void kernel_launch(void* const* d_in, const int* in_sizes, int n_in,
                              void* d_out, int out_size, void* d_ws, size_t ws_size,
                              hipStream_t stream) {
    const float* sino = (const float*)d_in[0];
    float* out = (float*)d_out;
    float* filtered = (float*)d_ws;                    // 261360 floats
    float2* cs_tab  = (float2*)((float*)d_ws + 262144); // 180 float2

    fbp_filter  <<<B_ * A_,   384, 0, stream>>>(sino, filtered, cs_tab);
    fbp_backproj<<<B_ * IMG_, 256, 0, stream>>>(filtered, cs_tab, out);
}